// Round 1
// baseline (808.777 us; speedup 1.0000x reference)
//
#include <hip/hip_runtime.h>

#define D_MODEL 1024
#define NHEADS  16
#define DKH     64
#define BATCH   2
#define SEQ     2048
#define MTOT    (BATCH*SEQ)     // 4096
#define NQKV    (3*D_MODEL)     // 3072
#define LDT     72              // 64 + 8 pad (ushorts) -> 144B row stride

typedef __bf16 bf16x8 __attribute__((ext_vector_type(8)));
typedef float  f32x4  __attribute__((ext_vector_type(4)));
typedef unsigned short u16x8 __attribute__((ext_vector_type(8)));
typedef unsigned short u16x4 __attribute__((ext_vector_type(4)));

#define MFMA(a,b,c) __builtin_amdgcn_mfma_f32_16x16x32_bf16(a,b,c,0,0,0)

__device__ __forceinline__ unsigned short f2bf(float f) {
  unsigned u = __builtin_bit_cast(unsigned, f);
  u += 0x7fffu + ((u >> 16) & 1u);   // RNE
  return (unsigned short)(u >> 16);
}

__device__ __forceinline__ bf16x8 ldfrag(const unsigned short* p) {
  return __builtin_bit_cast(bf16x8, *(const u16x8*)p);
}

// ---------------- fp32 -> bf16 convert ----------------
__global__ __launch_bounds__(256) void cvt_kernel(const float* __restrict__ src,
                                                  unsigned short* __restrict__ dst, int n4) {
  int i = blockIdx.x * blockDim.x + threadIdx.x;
  if (i >= n4) return;
  float4 f = ((const float4*)src)[i];
  u16x4 o;
  o[0] = f2bf(f.x); o[1] = f2bf(f.y); o[2] = f2bf(f.z); o[3] = f2bf(f.w);
  ((u16x4*)dst)[i] = o;
}

// ---------------- fused QKV projection: C = x @ Wqkv^T + b, scatter to Q/K/VT ----------------
__global__ __launch_bounds__(256) void qkv_gemm(const unsigned short* __restrict__ xbf,
                                                const unsigned short* __restrict__ wbf,   // 3072x1024 row-major
                                                const float* __restrict__ bq,
                                                const float* __restrict__ bk,
                                                const float* __restrict__ bv,
                                                unsigned short* __restrict__ Qo,   // [b][h][l][dk]
                                                unsigned short* __restrict__ Ko,   // [b][h][l][dk]
                                                unsigned short* __restrict__ VTo)  // [b][h][dk][l]
{
  __shared__ __attribute__((aligned(16))) unsigned short As[64*LDT];
  __shared__ __attribute__((aligned(16))) unsigned short Bs[64*LDT];
  const int tid  = threadIdx.x;
  const int wid  = tid >> 6;
  const int lane = tid & 63;
  const int lr   = lane & 15;
  const int lg   = lane >> 4;
  const int m0   = blockIdx.x * 64;
  const int n0   = blockIdx.y * 64;

  f32x4 zero = {0.f, 0.f, 0.f, 0.f};
  f32x4 acc[4];
  acc[0] = zero; acc[1] = zero; acc[2] = zero; acc[3] = zero;

  const int ko = lg * 8;
  for (int kt = 0; kt < D_MODEL/64; ++kt) {
    __syncthreads();
    for (int v = tid; v < 512; v += 256) {
      int row = v >> 3, c8 = (v & 7) * 8;
      *(u16x8*)&As[row*LDT + c8] = *(const u16x8*)&xbf[(size_t)(m0+row)*D_MODEL + kt*64 + c8];
      *(u16x8*)&Bs[row*LDT + c8] = *(const u16x8*)&wbf[(size_t)(n0+row)*D_MODEL + kt*64 + c8];
    }
    __syncthreads();
    bf16x8 a0 = ldfrag(&As[(wid*16+lr)*LDT + ko]);
    bf16x8 a1 = ldfrag(&As[(wid*16+lr)*LDT + 32 + ko]);
#pragma unroll
    for (int ct = 0; ct < 4; ++ct) {
      bf16x8 b0 = ldfrag(&Bs[(ct*16+lr)*LDT + ko]);
      bf16x8 b1 = ldfrag(&Bs[(ct*16+lr)*LDT + 32 + ko]);
      acc[ct] = MFMA(a0, b0, acc[ct]);
      acc[ct] = MFMA(a1, b1, acc[ct]);
    }
  }

  const int proj = n0 >> 10;            // block-uniform
  const int rem0 = n0 & 1023;           // h*64 (64-aligned)
  const int h    = rem0 >> 6;
  const float* bias = (proj == 0) ? bq : (proj == 1) ? bk : bv;

  if (proj < 2) {
    unsigned short* dst = (proj == 0) ? Qo : Ko;
#pragma unroll
    for (int ct = 0; ct < 4; ++ct) {
      int col = ct*16 + lr;             // dk
      float bval = bias[rem0 + col];
#pragma unroll
      for (int r = 0; r < 4; ++r) {
        int m  = m0 + wid*16 + lg*4 + r;
        int b_ = m >> 11, lq = m & (SEQ-1);
        dst[((size_t)((b_*NHEADS + h)*SEQ + lq))*DKH + col] = f2bf(acc[ct][r] + bval);
      }
    }
  } else {
    // transpose through LDS, then coalesced VT store
    __syncthreads();
#pragma unroll
    for (int ct = 0; ct < 4; ++ct) {
      int col = ct*16 + lr;             // dk
      float bval = bias[rem0 + col];
#pragma unroll
      for (int r = 0; r < 4; ++r) {
        int row = wid*16 + lg*4 + r;    // lq offset
        As[col*LDT + row] = f2bf(acc[ct][r] + bval);
      }
    }
    __syncthreads();
    int b_ = m0 >> 11, lq0 = m0 & (SEQ-1);
    int bh = b_*NHEADS + h;
    for (int v = tid; v < 512; v += 256) {
      int dk = v >> 3, c8 = (v & 7) * 8;
      *(u16x8*)&VTo[((size_t)(bh*DKH + dk))*SEQ + lq0 + c8] = *(const u16x8*)&As[dk*LDT + c8];
    }
  }
}

// ---------------- fused attention: S=QK^T/8, softmax (2-pass recompute), attn out, O=attn@V ----------------
__global__ __launch_bounds__(256) void attn_kernel(const unsigned short* __restrict__ Qw,
                                                   const unsigned short* __restrict__ Kw,
                                                   const unsigned short* __restrict__ VTw,
                                                   const int* __restrict__ mask,
                                                   float* __restrict__ attn_out,            // (B,H,L,L) fp32
                                                   unsigned short* __restrict__ OH)         // [b][l][h*64+dk] bf16
{
  __shared__ __attribute__((aligned(16))) unsigned short Qs[64*LDT];
  __shared__ __attribute__((aligned(16))) unsigned short Ks[64*LDT];
  __shared__ __attribute__((aligned(16))) unsigned short Vs[64*LDT];
  __shared__ __attribute__((aligned(16))) unsigned short Ps[64*LDT];
  __shared__ float invl[64];

  const int tid  = threadIdx.x;
  const int wid  = tid >> 6;
  const int lane = tid & 63;
  const int lr   = lane & 15;
  const int lg   = lane >> 4;
  const int q0   = blockIdx.x * 64;
  const int bh   = blockIdx.y;          // b*16+h
  const int b_   = bh >> 4;
  const int h    = bh & 15;

  const unsigned short* Qb = Qw  + (size_t)bh*SEQ*DKH;
  const unsigned short* Kb = Kw  + (size_t)bh*SEQ*DKH;
  const unsigned short* Vb = VTw + (size_t)bh*DKH*SEQ;

  for (int v = tid; v < 512; v += 256) {
    int row = v >> 3, c8 = (v & 7) * 8;
    *(u16x8*)&Qs[row*LDT + c8] = *(const u16x8*)&Qb[(size_t)(q0+row)*DKH + c8];
  }
  __syncthreads();

  const int ko = lg * 8;
  bf16x8 aq0 = ldfrag(&Qs[(wid*16+lr)*LDT + ko]);
  bf16x8 aq1 = ldfrag(&Qs[(wid*16+lr)*LDT + 32 + ko]);

  f32x4 zero = {0.f, 0.f, 0.f, 0.f};
  float lsum[4] = {0.f, 0.f, 0.f, 0.f};

  // ---- pass 1: row sums of exp(S) ----
  for (int kt = 0; kt < SEQ/64; ++kt) {
    __syncthreads();
    for (int v = tid; v < 512; v += 256) {
      int row = v >> 3, c8 = (v & 7) * 8;
      *(u16x8*)&Ks[row*LDT + c8] = *(const u16x8*)&Kb[(size_t)(kt*64+row)*DKH + c8];
    }
    __syncthreads();
#pragma unroll
    for (int ct = 0; ct < 4; ++ct) {
      f32x4 acc = zero;
      bf16x8 b0 = ldfrag(&Ks[(ct*16+lr)*LDT + ko]);
      bf16x8 b1 = ldfrag(&Ks[(ct*16+lr)*LDT + 32 + ko]);
      acc = MFMA(aq0, b0, acc);
      acc = MFMA(aq1, b1, acc);
      int kg = kt*64 + ct*16 + lr;
      bool live = mask[b_*SEQ + kg] != 0;
#pragma unroll
      for (int r = 0; r < 4; ++r) {
        float s = live ? acc[r]*0.125f : -1e9f;
        lsum[r] += __expf(s);
      }
    }
  }
#pragma unroll
  for (int r = 0; r < 4; ++r) {
    float s = lsum[r];
    s += __shfl_xor(s, 1); s += __shfl_xor(s, 2);
    s += __shfl_xor(s, 4); s += __shfl_xor(s, 8);
    if (lr == 0) invl[wid*16 + lg*4 + r] = 1.0f / s;
  }
  __syncthreads();

  float il[4];
  {
    int rowb = wid*16 + lg*4;
    il[0] = invl[rowb+0]; il[1] = invl[rowb+1];
    il[2] = invl[rowb+2]; il[3] = invl[rowb+3];
  }

  f32x4 oacc[4];
  oacc[0] = zero; oacc[1] = zero; oacc[2] = zero; oacc[3] = zero;

  // ---- pass 2: recompute S, write attn, accumulate O ----
  for (int kt = 0; kt < SEQ/64; ++kt) {
    __syncthreads();
    for (int v = tid; v < 512; v += 256) {
      int row = v >> 3, c8 = (v & 7) * 8;
      *(u16x8*)&Ks[row*LDT + c8] = *(const u16x8*)&Kb[(size_t)(kt*64+row)*DKH + c8];
      *(u16x8*)&Vs[row*LDT + c8] = *(const u16x8*)&Vb[(size_t)row*SEQ + kt*64 + c8];
    }
    __syncthreads();
#pragma unroll
    for (int ct = 0; ct < 4; ++ct) {
      f32x4 acc = zero;
      bf16x8 b0 = ldfrag(&Ks[(ct*16+lr)*LDT + ko]);
      bf16x8 b1 = ldfrag(&Ks[(ct*16+lr)*LDT + 32 + ko]);
      acc = MFMA(aq0, b0, acc);
      acc = MFMA(aq1, b1, acc);
      int kg = kt*64 + ct*16 + lr;
      bool live = mask[b_*SEQ + kg] != 0;
#pragma unroll
      for (int r = 0; r < 4; ++r) {
        float s = live ? acc[r]*0.125f : -1e9f;
        float p = __expf(s);
        int row = wid*16 + lg*4 + r;
        float a = p * il[r];
        attn_out[(size_t)(bh*SEQ + q0 + row)*SEQ + kg] = a;
        Ps[row*LDT + ct*16 + lr] = f2bf(a);
      }
    }
    __syncthreads();
    bf16x8 pa0 = ldfrag(&Ps[(wid*16+lr)*LDT + ko]);
    bf16x8 pa1 = ldfrag(&Ps[(wid*16+lr)*LDT + 32 + ko]);
#pragma unroll
    for (int ct = 0; ct < 4; ++ct) {
      bf16x8 v0 = ldfrag(&Vs[(ct*16+lr)*LDT + ko]);
      bf16x8 v1 = ldfrag(&Vs[(ct*16+lr)*LDT + 32 + ko]);
      oacc[ct] = MFMA(pa0, v0, oacc[ct]);
      oacc[ct] = MFMA(pa1, v1, oacc[ct]);
    }
  }

  // write O tile as bf16 into OH (row-major 4096 x 1024, col = h*64+dk)
#pragma unroll
  for (int ct = 0; ct < 4; ++ct) {
    int dk = ct*16 + lr;
#pragma unroll
    for (int r = 0; r < 4; ++r) {
      int q = q0 + wid*16 + lg*4 + r;
      OH[(size_t)(b_*SEQ + q)*D_MODEL + h*DKH + dk] = f2bf(oacc[ct][r]);
    }
  }
}

// ---------------- output projection: out = OH @ Wo^T + bo (fp32 out) ----------------
__global__ __launch_bounds__(256) void out_gemm(const unsigned short* __restrict__ OH,
                                                const unsigned short* __restrict__ wo,
                                                const float* __restrict__ bo,
                                                float* __restrict__ out)
{
  __shared__ __attribute__((aligned(16))) unsigned short As[64*LDT];
  __shared__ __attribute__((aligned(16))) unsigned short Bs[64*LDT];
  const int tid  = threadIdx.x;
  const int wid  = tid >> 6;
  const int lane = tid & 63;
  const int lr   = lane & 15;
  const int lg   = lane >> 4;
  const int m0   = blockIdx.x * 64;
  const int n0   = blockIdx.y * 64;

  f32x4 zero = {0.f, 0.f, 0.f, 0.f};
  f32x4 acc[4];
  acc[0] = zero; acc[1] = zero; acc[2] = zero; acc[3] = zero;

  const int ko = lg * 8;
  for (int kt = 0; kt < D_MODEL/64; ++kt) {
    __syncthreads();
    for (int v = tid; v < 512; v += 256) {
      int row = v >> 3, c8 = (v & 7) * 8;
      *(u16x8*)&As[row*LDT + c8] = *(const u16x8*)&OH[(size_t)(m0+row)*D_MODEL + kt*64 + c8];
      *(u16x8*)&Bs[row*LDT + c8] = *(const u16x8*)&wo[(size_t)(n0+row)*D_MODEL + kt*64 + c8];
    }
    __syncthreads();
    bf16x8 a0 = ldfrag(&As[(wid*16+lr)*LDT + ko]);
    bf16x8 a1 = ldfrag(&As[(wid*16+lr)*LDT + 32 + ko]);
#pragma unroll
    for (int ct = 0; ct < 4; ++ct) {
      bf16x8 b0 = ldfrag(&Bs[(ct*16+lr)*LDT + ko]);
      bf16x8 b1 = ldfrag(&Bs[(ct*16+lr)*LDT + 32 + ko]);
      acc[ct] = MFMA(a0, b0, acc[ct]);
      acc[ct] = MFMA(a1, b1, acc[ct]);
    }
  }
#pragma unroll
  for (int ct = 0; ct < 4; ++ct) {
    int n = n0 + ct*16 + lr;
    float bval = bo[n];
#pragma unroll
    for (int r = 0; r < 4; ++r) {
      int m = m0 + wid*16 + lg*4 + r;
      out[(size_t)m*D_MODEL + n] = acc[ct][r] + bval;
    }
  }
}

extern "C" void kernel_launch(void* const* d_in, const int* in_sizes, int n_in,
                              void* d_out, int out_size, void* d_ws, size_t ws_size,
                              hipStream_t stream) {
  const float* x    = (const float*)d_in[0];
  const int*   mask = (const int*)  d_in[1];
  const float* Wq   = (const float*)d_in[2];
  const float* bq   = (const float*)d_in[3];
  const float* Wk   = (const float*)d_in[4];
  const float* bk   = (const float*)d_in[5];
  const float* Wv   = (const float*)d_in[6];
  const float* bv   = (const float*)d_in[7];
  const float* Wo   = (const float*)d_in[8];
  const float* bo   = (const float*)d_in[9];

  float* out0 = (float*)d_out;
  float* attn = out0 + (size_t)MTOT * D_MODEL;

  unsigned short* ws   = (unsigned short*)d_ws;
  unsigned short* xbf  = ws;                                   // 4096*1024
  unsigned short* wqkv = xbf  + (size_t)MTOT * D_MODEL;        // 3072*1024
  unsigned short* wob  = wqkv + (size_t)NQKV * D_MODEL;        // 1024*1024
  unsigned short* Qw   = wob  + (size_t)D_MODEL * D_MODEL;     // 4096*1024 (per-head)
  unsigned short* Kw   = Qw   + (size_t)MTOT * D_MODEL;
  unsigned short* VTw  = Kw   + (size_t)MTOT * D_MODEL;
  unsigned short* OH   = VTw  + (size_t)MTOT * D_MODEL;        // total 48 MiB

  // fp32 -> bf16 packs
  cvt_kernel<<<4096, 256, 0, stream>>>(x,  xbf, MTOT*D_MODEL/4);
  cvt_kernel<<<1024, 256, 0, stream>>>(Wq, wqkv,                 D_MODEL*D_MODEL/4);
  cvt_kernel<<<1024, 256, 0, stream>>>(Wk, wqkv +   D_MODEL*D_MODEL, D_MODEL*D_MODEL/4);
  cvt_kernel<<<1024, 256, 0, stream>>>(Wv, wqkv + 2*D_MODEL*D_MODEL, D_MODEL*D_MODEL/4);
  cvt_kernel<<<1024, 256, 0, stream>>>(Wo, wob, D_MODEL*D_MODEL/4);

  qkv_gemm<<<dim3(MTOT/64, NQKV/64), 256, 0, stream>>>(xbf, wqkv, bq, bk, bv, Qw, Kw, VTw);
  attn_kernel<<<dim3(SEQ/64, BATCH*NHEADS), 256, 0, stream>>>(Qw, Kw, VTw, mask, attn, OH);
  out_gemm<<<dim3(MTOT/64, D_MODEL/64), 256, 0, stream>>>(OH, wob, bo, out0);
}